// Round 9
// baseline (115.036 us; speedup 1.0000x reference)
//
#include <hip/hip_runtime.h>
#include <cmath>

#define T_TOKENS 16384
#define DIM 2048
#define HH 64
#define NG 4
#define EPG 16
#define NE 64
#define NJ 132
#define NT 9            // n-tiles of 16 (144 padded)
#define BM 32           // tokens per block
#define BK 64           // k per iteration (2 ksteps of 32)
#define NITER (DIM / BK)    // 32
#define WCELLS 1152     // uint4 cells per weight slab (18 groups of 64)
#define TAU 0.02f
#define KEPS 1.5e-3f

typedef __attribute__((ext_vector_type(8))) short bf16x8;
typedef __attribute__((ext_vector_type(4))) float f32x4;

// ws float-offsets
#define WF_FLOATS (64 * NT * 64 * 4)    // fragment-linear bf16 weights, 64 ksteps
#define SUM_OFF WF_FLOATS               // 128 floats: usage, rp
#define CNT_OFF (SUM_OFF + 128)
#define LIST_OFF (CNT_OFF + 4)          // int4 entries (16B aligned)

static __device__ inline unsigned bf16rne(float x) {
    unsigned u = __float_as_uint(x);
    return (u + 0x7FFFu + ((u >> 16) & 1u)) >> 16;
}
static __device__ inline unsigned pk2trunc(float a, float b) {
    return (__float_as_uint(a) >> 16) | (__float_as_uint(b) & 0xFFFF0000u);
}

#define GLOAD_LDS(gsrc, ldst) \
    __builtin_amdgcn_global_load_lds( \
        (const __attribute__((address_space(1))) void*)(gsrc), \
        (__attribute__((address_space(3))) void*)(ldst), 16, 0, 0)

// Build fragment-linear bf16 weight buffer: [kstep 64][ntile 9][lane 64][16B]
__global__ void moe_prep(const float* __restrict__ Wg, const float* __restrict__ We,
                         const float* __restrict__ W1, float* __restrict__ ws,
                         float* __restrict__ sums, int* __restrict__ cnt) {
    int bid = blockIdx.x;                 // 576
    int kstep = bid / NT, nt = bid % NT;
    int lane = threadIdx.x;               // 64
    if (bid == 0) {
        sums[lane] = 0.f; sums[64 + lane] = 0.f;
        if (lane == 0) *cnt = 0;
    }
    int row = nt * 16 + (lane & 15);
    int k0 = kstep * 32 + (lane >> 4) * 8;
    const float* src = nullptr;
    if (row < HH)            src = W1 + (size_t)row * DIM;
    else if (row < HH + NG)  src = Wg + (size_t)(row - HH) * DIM;
    else if (row < NJ)       src = We + (size_t)(row - HH - NG) * DIM;
    unsigned r0 = 0, r1 = 0, r2 = 0, r3 = 0;
    if (src) {
        r0 = bf16rne(src[k0 + 0]) | (bf16rne(src[k0 + 1]) << 16);
        r1 = bf16rne(src[k0 + 2]) | (bf16rne(src[k0 + 3]) << 16);
        r2 = bf16rne(src[k0 + 4]) | (bf16rne(src[k0 + 5]) << 16);
        r3 = bf16rne(src[k0 + 6]) | (bf16rne(src[k0 + 7]) << 16);
    }
    ((uint4*)ws)[(size_t)(kstep * NT + nt) * 64 + lane] = make_uint4(r0, r1, r2, r3);
}

// Fused staged GEMM + epilogue: 512 blocks x 512 threads (8 waves), 32 tokens/block.
// Weights: async global_load_lds DMA (no VGPR round trip). x: reg-convert + paired b128 write.
__global__ __launch_bounds__(512, 4) void moe_fused(
    const float* __restrict__ x, const float* __restrict__ wfrag,
    const float* __restrict__ b1, const float* __restrict__ W2,
    const float* __restrict__ b2, const int* __restrict__ minE,
    const int* __restrict__ maxE, float* __restrict__ out,
    float* __restrict__ sums, int* __restrict__ cnt, int4* __restrict__ list) {
    __shared__ uint4 xs[2][4][64];       // [buf][row=mhalf*2+ks][swizzled col]  8 KB
    __shared__ uint4 wsd[2][18][64];     // [buf][cellgrp][lane]  36 KB  (DMA dest, linear)
    __shared__ float slog[BM][145];
    __shared__ float rp_s[BM * 17];
    __shared__ float sc_n1[BM], sc_n2[BM], sc_u2[BM];
    __shared__ int   sc_e1[BM], sc_e2[BM];
    __shared__ float s_usage[NE], s_rp[NE];

    const int tid = threadIdx.x;          // 0..511
    const int wave = tid >> 6, lane = tid & 63;
    const int l15 = lane & 15, lq = lane >> 4;
    const int T0 = blockIdx.x * BM;

    if (tid < NE) { s_usage[tid] = 0.f; s_rp[tid] = 0.f; }

    // ---- x staging role: thread covers token stok, float4 kq of each 64-k slab.
    // Writer (even kq) combines own 4 floats + partner's (shfl_xor 1) into one b128.
    // cell: row = (stok>>4)*2 + (kq>>3); ksub = (kq>>1)&3; tok16 = stok&15;
    //       col = ksub*16 + ((tok16 + 2*ksub + 4*row) & 15)   [bijective per row]
    // Reader (lane l, row r) uses col = (l>>4)*16 + (((l&15) + 2*(l>>4) + 4*r) & 15).
    const int stok = tid >> 4;            // 0..31
    const int kq   = tid & 15;            // 0..15
    const float* xg = x + (size_t)(T0 + stok) * DIM + kq * 4;
    const bool xwriter = !(kq & 1);
    const int xrow = (stok >> 4) * 2 + (kq >> 3);
    const int xksub = (kq >> 1) & 3;
    const int xcol = xksub * 16 + (((stok & 15) + 2 * xksub + 4 * xrow) & 15);

    // ---- weight DMA role: wave w issues cell-groups {w*2, w*2+1} (+16/17 for waves 0,1)
    const uint4* wg = (const uint4*)wfrag;

    // ---- compute role
    const int mhalf = wave & 1, g = wave >> 1;
    const int nt0 = g, nt1 = g + 4;
    const bool has3 = (g == 0);
    const int rcol0 = lq * 16;            // + per-row rotate applied below

    f32x4 acc0 = (f32x4){0.f,0.f,0.f,0.f};
    f32x4 acc1 = (f32x4){0.f,0.f,0.f,0.f};
    f32x4 acc2 = (f32x4){0.f,0.f,0.f,0.f};

    // prologue: stage iter 0 into buf 0
    {
        float4 xv = *(const float4*)xg;
        const uint4* wslab = wg;
        GLOAD_LDS(wslab + (wave * 2) * 64 + lane,     &wsd[0][wave * 2][0]);
        GLOAD_LDS(wslab + (wave * 2 + 1) * 64 + lane, &wsd[0][wave * 2 + 1][0]);
        if (wave < 2) GLOAD_LDS(wslab + (16 + wave) * 64 + lane, &wsd[0][16 + wave][0]);
        unsigned p0 = pk2trunc(xv.x, xv.y), p1 = pk2trunc(xv.z, xv.w);
        unsigned q0 = __shfl_xor(p0, 1), q1 = __shfl_xor(p1, 1);
        if (xwriter) xs[0][xrow][xcol] = make_uint4(p0, p1, q0, q1);
        __syncthreads();
    }

    #pragma unroll 2
    for (int it = 0; it < NITER; ++it) {
        const int cur = it & 1;
        const bool more = (it + 1 < NITER);
        unsigned p0, p1, q0, q1;
        if (more) {   // issue next-iter loads early (x to regs, w via async DMA)
            float4 xv = *(const float4*)(xg + (it + 1) * BK);
            const uint4* wslab = wg + (size_t)(it + 1) * WCELLS;
            const int nxt = cur ^ 1;
            GLOAD_LDS(wslab + (wave * 2) * 64 + lane,     &wsd[nxt][wave * 2][0]);
            GLOAD_LDS(wslab + (wave * 2 + 1) * 64 + lane, &wsd[nxt][wave * 2 + 1][0]);
            if (wave < 2) GLOAD_LDS(wslab + (16 + wave) * 64 + lane, &wsd[nxt][16 + wave][0]);
            p0 = pk2trunc(xv.x, xv.y); p1 = pk2trunc(xv.z, xv.w);
        }
        // compute on cur buffer
        {
            const uint4* wb = &wsd[cur][0][0];
            #pragma unroll
            for (int ks = 0; ks < 2; ++ks) {
                const int r = mhalf * 2 + ks;
                const int rc = rcol0 + ((l15 + 2 * lq + 4 * r) & 15);
                bf16x8 af = *(const bf16x8*)&xs[cur][r][rc];
                bf16x8 b0 = *(const bf16x8*)&wb[(ks * 9 + nt0) * 64 + lane];
                bf16x8 b1v = *(const bf16x8*)&wb[(ks * 9 + nt1) * 64 + lane];
                acc0 = __builtin_amdgcn_mfma_f32_16x16x32_bf16(af, b0, acc0, 0, 0, 0);
                acc1 = __builtin_amdgcn_mfma_f32_16x16x32_bf16(af, b1v, acc1, 0, 0, 0);
                if (has3) {
                    bf16x8 b2v = *(const bf16x8*)&wb[(ks * 9 + 8) * 64 + lane];
                    acc2 = __builtin_amdgcn_mfma_f32_16x16x32_bf16(af, b2v, acc2, 0, 0, 0);
                }
            }
        }
        if (more) {   // paired b128 x-write into next buffer
            q0 = __shfl_xor(p0, 1); q1 = __shfl_xor(p1, 1);
            if (xwriter) xs[cur ^ 1][xrow][xcol] = make_uint4(p0, p1, q0, q1);
        }
        __syncthreads();
    }

    // dump accumulators: row(token) = mhalf*16 + lq*4 + r, col = tile*16 + l15
    #pragma unroll
    for (int r = 0; r < 4; ++r) {
        const int row = mhalf * 16 + lq * 4 + r;
        slog[row][nt0 * 16 + l15] = acc0[r];
        slog[row][nt1 * 16 + l15] = acc1[r];
        if (has3) slog[row][8 * 16 + l15] = acc2[r];
    }
    __syncthreads();

    // parallel epilogue: 32 groups of 16 lanes; group t handles token t
    {
        const int t = tid >> 4;       // 0..31
        const int q = tid & 15;
        const int tok = T0 + t;
        const float* o = slog[t];

        float4 b1v = ((const float4*)b1)[q];
        float4 w2v = ((const float4*)W2)[q];
        float part;
        {
            float h0 = o[q * 4 + 0] + b1v.x; h0 = h0 > 0.f ? h0 : 0.f;
            float h1 = o[q * 4 + 1] + b1v.y; h1 = h1 > 0.f ? h1 : 0.f;
            float h2 = o[q * 4 + 2] + b1v.z; h2 = h2 > 0.f ? h2 : 0.f;
            float h3 = o[q * 4 + 3] + b1v.w; h3 = h3 > 0.f ? h3 : 0.f;
            part = h0 * w2v.x + h1 * w2v.y + h2 * w2v.z + h3 * w2v.w;
        }
        #pragma unroll
        for (int off = 8; off; off >>= 1) part += __shfl_xor(part, off, 16);
        float z = b2[0] + part;
        float c = 1.f / (1.f + expf(-z));
        int mx = maxE[0], mn = minE[0];
        float y = c * (float)mx;
        int k = (int)y; k = k < mn ? mn : (k > mx ? mx : k);
        int kl = (int)(y - KEPS); kl = kl < mn ? mn : (kl > mx ? mx : kl);
        int kh = (int)(y + KEPS); kh = kh < mn ? mn : (kh > mx ? mx : kh);
        bool flagK = (kl != kh);
        float u2 = (k >= 2) ? 1.f : 0.f;

        float gl0 = o[HH + 0], gl1 = o[HH + 1], gl2 = o[HH + 2], gl3 = o[HH + 3];
        float gm = gl0; int gi = 0;
        if (gl1 > gm) { gm = gl1; gi = 1; }
        if (gl2 > gm) { gm = gl2; gi = 2; }
        if (gl3 > gm) { gm = gl3; gi = 3; }
        float g2 = -INFINITY;
        if (gi != 0 && gl0 > g2) g2 = gl0;
        if (gi != 1 && gl1 > g2) g2 = gl1;
        if (gi != 2 && gl2 > g2) g2 = gl2;
        if (gi != 3 && gl3 > g2) g2 = gl3;
        bool flagG = (gm - g2) < TAU;
        float gsum = expf(gl0 - gm) + expf(gl1 - gm) + expf(gl2 - gm) + expf(gl3 - gm);
        float gp = 1.f / gsum;

        float el = o[HH + NG + gi * EPG + q];
        float v1v = el; int i1 = q;
        #pragma unroll
        for (int off = 8; off; off >>= 1) {
            float ov = __shfl_xor(v1v, off, 16);
            int   oi = __shfl_xor(i1, off, 16);
            if (ov > v1v || (ov == v1v && oi < i1)) { v1v = ov; i1 = oi; }
        }
        float v2v = (q == i1) ? -INFINITY : el; int i2 = q;
        #pragma unroll
        for (int off = 8; off; off >>= 1) {
            float ov = __shfl_xor(v2v, off, 16);
            int   oi = __shfl_xor(i2, off, 16);
            if (ov > v2v || (ov == v2v && oi < i2)) { v2v = ov; i2 = oi; }
        }
        float e3v = (q == i1 || q == i2) ? -INFINITY : el;
        #pragma unroll
        for (int off = 8; off; off >>= 1)
            e3v = fmaxf(e3v, __shfl_xor(e3v, off, 16));
        bool flagE = ((v1v - v2v) < TAU) || (u2 > 0.f && (v2v - e3v) < TAU);

        float ep = expf(el - v1v);
        float es = ep;
        #pragma unroll
        for (int off = 8; off; off >>= 1) es += __shfl_xor(es, off, 16);
        float inv = 1.f / es;
        rp_s[t * 17 + q] = gp * ep * inv;

        if (q == 0) {
            float v1p = inv;
            float v2p = expf(v2v - v1v) * inv;
            float denom = v1p + v2p * u2;
            sc_n1[t] = v1p / denom; sc_n2[t] = v2p * u2 / denom; sc_u2[t] = u2;
            sc_e1[t] = gi * EPG + i1; sc_e2[t] = gi * EPG + i2;
            if (flagK || flagG || flagE) {
                int p = atomicAdd(cnt, 1);
                int fl = (flagG ? 1 : 0) | (flagE ? 2 : 0) | (flagK ? 4 : 0);
                list[p] = make_int4(tok, fl, (int)u2, 0);
            }
        }
    }
    __syncthreads();

    float* outD = out;
    float* outC = out + (size_t)T_TOKENS * NE;
    float* outR = out + (size_t)2 * T_TOKENS * NE;
    for (int idx = tid; idx < BM * NE; idx += 512) {
        int t = idx >> 6, e = idx & 63;
        int e1i = sc_e1[t], e2i = sc_e2[t];
        int gi = e1i >> 4;
        float disp = (e == e1i ? 1.f : 0.f) + (e == e2i ? sc_u2[t] : 0.f);
        float comb = (e == e1i ? sc_n1[t] : 0.f) + (e == e2i ? sc_n2[t] : 0.f);
        float rpv  = ((e >> 4) == gi) ? rp_s[t * 17 + (e & 15)] : 0.f;
        size_t ob = (size_t)(T0 + t) * NE + e;
        outD[ob] = disp; outC[ob] = comb; outR[ob] = rpv;
        atomicAdd(&s_usage[e], disp);
        atomicAdd(&s_rp[e], rpv);
    }
    __syncthreads();
    if (tid < NE) {
        atomicAdd(&sums[tid], s_usage[tid]);
        atomicAdd(&sums[NE + tid], s_rp[tid]);
    }
}

// parallel fixup: one block (4 waves) per flagged token
__global__ __launch_bounds__(256, 4) void moe_fix(
    const float* __restrict__ x, const float* __restrict__ Wg,
    const float* __restrict__ We, const float* __restrict__ W1,
    const float* __restrict__ b1, const float* __restrict__ W2,
    const float* __restrict__ b2, const int* __restrict__ minE,
    const int* __restrict__ maxE, float* __restrict__ out,
    float* __restrict__ sums, const int* __restrict__ cnt,
    const int4* __restrict__ list) {
    __shared__ float gl_s[NG];
    __shared__ float h_s[HH];
    __shared__ float el_s[EPG];
    __shared__ float rp_row[EPG];
    __shared__ int   s_gi;
    __shared__ float s_u2, s_gp;
    __shared__ int   s_e1, s_e2;
    __shared__ float s_n1, s_n2;

    const int tid = threadIdx.x;
    const int wave = tid >> 6, lane = tid & 63;
    const int n = *cnt;

    for (int i = blockIdx.x; i < n; i += gridDim.x) {
        const int4 ent = list[i];
        const int tok = ent.x, fl = ent.y;
        const float u2_in = (float)ent.z;

        const float* xrow = x + (size_t)tok * DIM;
        float xr[32];
        #pragma unroll
        for (int m = 0; m < 32; ++m) xr[m] = xrow[lane + m * 64];

        auto dotf = [&](const float* w) -> float {
            float s = 0.f;
            #pragma unroll
            for (int m = 0; m < 32; ++m) s = fmaf(xr[m], w[lane + m * 64], s);
            #pragma unroll
            for (int off = 32; off; off >>= 1) s += __shfl_xor(s, off, 64);
            return s;
        };

        {
            float g = dotf(Wg + (size_t)wave * DIM);
            if (lane == 0) gl_s[wave] = g;
        }
        if (fl & 4) {
            for (int j = wave; j < HH; j += 4) {
                float hv = dotf(W1 + (size_t)j * DIM);
                if (lane == 0) h_s[j] = hv;
            }
        }
        __syncthreads();

        if (tid == 0) {
            float gm = -INFINITY; int gi = 0;
            #pragma unroll
            for (int g = 0; g < NG; ++g)
                if (gl_s[g] > gm) { gm = gl_s[g]; gi = g; }
            float gsum = 0.f;
            #pragma unroll
            for (int g = 0; g < NG; ++g) gsum += expf(gl_s[g] - gm);
            s_gp = 1.f / gsum;
            s_gi = gi;
            float u2 = u2_in;
            if (fl & 4) {
                float z = b2[0];
                for (int j = 0; j < HH; ++j) {
                    float h = h_s[j] + b1[j];
                    z = fmaf(W2[j], h > 0.f ? h : 0.f, z);
                }
                float c = 1.f / (1.f + expf(-z));
                int mx = maxE[0], mn = minE[0];
                int k = (int)(c * (float)mx);
                k = k < mn ? mn : (k > mx ? mx : k);
                u2 = (k >= 2) ? 1.f : 0.f;
            }
            s_u2 = u2;
        }
        __syncthreads();

        const int gi = s_gi;
        for (int j = wave; j < EPG; j += 4) {
            float e = dotf(We + (size_t)(gi * EPG + j) * DIM);
            if (lane == 0) el_s[j] = e;
        }
        __syncthreads();

        if (tid == 0) {
            float e1 = -INFINITY, e2v = -INFINITY; int i1 = 0, i2 = 0;
            #pragma unroll
            for (int j = 0; j < EPG; ++j) {
                float v = el_s[j];
                if (v > e1)       { e2v = e1; i2 = i1; e1 = v; i1 = j; }
                else if (v > e2v) { e2v = v; i2 = j; }
            }
            float es = 0.f;
            #pragma unroll
            for (int j = 0; j < EPG; ++j) {
                float e = expf(el_s[j] - e1);
                rp_row[j] = e;
                es += e;
            }
            float inv = 1.f / es;
            float gp = s_gp;
            #pragma unroll
            for (int j = 0; j < EPG; ++j) rp_row[j] *= inv * gp;
            float v1 = expf(el_s[i1] - e1) * inv;
            float v2 = expf(el_s[i2] - e1) * inv;
            float u2 = s_u2;
            float denom = v1 + v2 * u2;
            s_n1 = v1 / denom; s_n2 = v2 * u2 / denom;
            s_e1 = gi * EPG + i1; s_e2 = gi * EPG + i2;
        }
        __syncthreads();

        if (tid < NE) {
            const int e = tid;
            float u2 = s_u2;
            float newD = (e == s_e1 ? 1.f : 0.f) + (e == s_e2 ? u2 : 0.f);
            float newC = (e == s_e1 ? s_n1 : 0.f) + (e == s_e2 ? s_n2 : 0.f);
            float newR = ((e >> 4) == gi) ? rp_row[e & 15] : 0.f;
            size_t ob = (size_t)tok * NE + e;
            float oldD = out[ob];
            float oldR = out[(size_t)2 * T_TOKENS * NE + ob];
            out[ob] = newD;
            out[(size_t)T_TOKENS * NE + ob] = newC;
            out[(size_t)2 * T_TOKENS * NE + ob] = newR;
            float dD = newD - oldD, dR = newR - oldR;
            if (dD != 0.f) atomicAdd(&sums[e], dD);
            if (dR != 0.f) atomicAdd(&sums[NE + e], dR);
        }
        __syncthreads();
    }
}

__global__ void moe_finalize(const float* __restrict__ sums, float* __restrict__ out) {
    int l = threadIdx.x;
    float v = sums[l] * sums[NE + l];
    #pragma unroll
    for (int off = 32; off; off >>= 1) v += __shfl_down(v, off, 64);
    if (l == 0) {
        float N = (float)T_TOKENS;
        out[(size_t)3 * T_TOKENS * NE] = v * (float)NE / (N * N);
    }
}

extern "C" void kernel_launch(void* const* d_in, const int* in_sizes, int n_in,
                              void* d_out, int out_size, void* d_ws, size_t ws_size,
                              hipStream_t stream) {
    const float* x  = (const float*)d_in[0];
    const float* Wg = (const float*)d_in[1];
    const float* We = (const float*)d_in[2];
    const float* W1 = (const float*)d_in[3];
    const float* b1 = (const float*)d_in[4];
    const float* W2 = (const float*)d_in[5];
    const float* b2 = (const float*)d_in[6];
    const int* minE = (const int*)d_in[7];
    const int* maxE = (const int*)d_in[8];
    float* out = (float*)d_out;
    float* ws  = (float*)d_ws;

    float* wfrag = ws;
    float* sums  = ws + SUM_OFF;
    int*   cnt   = (int*)(ws + CNT_OFF);
    int4*  list  = (int4*)(ws + LIST_OFF);

    moe_prep<<<64 * NT, 64, 0, stream>>>(Wg, We, W1, wfrag, sums, cnt);
    moe_fused<<<T_TOKENS / BM, 512, 0, stream>>>(x, wfrag, b1, W2, b2, minE, maxE,
                                                 out, sums, cnt, list);
    moe_fix<<<2048, 256, 0, stream>>>(x, Wg, We, W1, b1, W2, b2, minE, maxE,
                                      out, sums, cnt, list);
    moe_finalize<<<1, 64, 0, stream>>>(sums, out);
}

// Round 10
// 114.135 us; speedup vs baseline: 1.0079x; 1.0079x over previous
//
#include <hip/hip_runtime.h>
#include <cmath>

#define T_TOKENS 16384
#define DIM 2048
#define HH 64
#define NG 4
#define EPG 16
#define NE 64
#define NJ 132
#define NT 9            // n-tiles of 16 (144 padded)
#define BM 32           // tokens per block
#define BK 64           // k per iteration (2 ksteps of 32)
#define NITER (DIM / BK)    // 32
#define WCELLS 1152     // uint4 cells per weight slab (2 ksteps * 9 nt * 64)
#define BUFB 26624      // bytes per staging buffer: 18KB w + 8KB x
#define TAU 0.02f
#define KEPS 1.5e-3f

typedef __attribute__((ext_vector_type(8))) short bf16x8;
typedef __attribute__((ext_vector_type(4))) float f32x4;

// ws float-offsets
#define WF_FLOATS (64 * NT * 64 * 4)    // fragment-linear bf16 weights, 64 ksteps
#define SUM_OFF WF_FLOATS               // 128 floats: usage, rp
#define CNT_OFF (SUM_OFF + 128)
#define LIST_OFF (CNT_OFF + 4)          // int4 entries (16B aligned)

static __device__ inline unsigned bf16rne(float x) {
    unsigned u = __float_as_uint(x);
    return (u + 0x7FFFu + ((u >> 16) & 1u)) >> 16;
}

#define GLOAD_LDS(gsrc, ldst) \
    __builtin_amdgcn_global_load_lds( \
        (const __attribute__((address_space(1))) void*)(gsrc), \
        (__attribute__((address_space(3))) void*)(ldst), 16, 0, 0)

// Build fragment-linear bf16 weight buffer: [kstep 64][ntile 9][lane 64][16B]
__global__ void moe_prep(const float* __restrict__ Wg, const float* __restrict__ We,
                         const float* __restrict__ W1, float* __restrict__ ws,
                         float* __restrict__ sums, int* __restrict__ cnt) {
    int bid = blockIdx.x;                 // 576
    int kstep = bid / NT, nt = bid % NT;
    int lane = threadIdx.x;               // 64
    if (bid == 0) {
        sums[lane] = 0.f; sums[64 + lane] = 0.f;
        if (lane == 0) *cnt = 0;
    }
    int row = nt * 16 + (lane & 15);
    int k0 = kstep * 32 + (lane >> 4) * 8;
    const float* src = nullptr;
    if (row < HH)            src = W1 + (size_t)row * DIM;
    else if (row < HH + NG)  src = Wg + (size_t)(row - HH) * DIM;
    else if (row < NJ)       src = We + (size_t)(row - HH - NG) * DIM;
    unsigned r0 = 0, r1 = 0, r2 = 0, r3 = 0;
    if (src) {
        r0 = bf16rne(src[k0 + 0]) | (bf16rne(src[k0 + 1]) << 16);
        r1 = bf16rne(src[k0 + 2]) | (bf16rne(src[k0 + 3]) << 16);
        r2 = bf16rne(src[k0 + 4]) | (bf16rne(src[k0 + 5]) << 16);
        r3 = bf16rne(src[k0 + 6]) | (bf16rne(src[k0 + 7]) << 16);
    }
    ((uint4*)ws)[(size_t)(kstep * NT + nt) * 64 + lane] = make_uint4(r0, r1, r2, r3);
}

// Fused pipelined GEMM + epilogue: 512 blocks x 512 threads (8 waves), 32 tokens/block.
// ALL staging is global_load_lds; 3 LDS buffers, prefetch distance 2,
// counted s_waitcnt vmcnt(N) + raw s_barrier (never drain to 0 mid-loop).
__global__ __launch_bounds__(512, 4) void moe_fused(
    const float* __restrict__ x, const float* __restrict__ wfrag,
    const float* __restrict__ b1, const float* __restrict__ W2,
    const float* __restrict__ b2, const int* __restrict__ minE,
    const int* __restrict__ maxE, float* __restrict__ out,
    float* __restrict__ sums, int* __restrict__ cnt, int4* __restrict__ list) {
    __shared__ __align__(16) char smem[3 * BUFB];   // 3 staging bufs; buf0 reused as slog, buf1 as rp_s
    __shared__ float sc_n1[BM], sc_n2[BM], sc_u2[BM];
    __shared__ int   sc_e1[BM], sc_e2[BM];
    __shared__ float s_usage[NE], s_rp[NE];

    const int tid = threadIdx.x;          // 0..511
    const int wave = tid >> 6, lane = tid & 63;
    const int l15 = lane & 15, lq = lane >> 4;
    const int T0 = blockIdx.x * BM;

    if (tid < NE) { s_usage[tid] = 0.f; s_rp[tid] = 0.f; }

    // ---- staging roles (all DMA) ----
    // w: wave w stages groups {2w, 2w+1}; waves 0,1 additionally groups 16,17.
    // x: wave w stages tokens [w*4, w*4+4): lane l covers token w*4+(l>>4),
    //    16B unit q=(l&15) holding GLOBAL k4 = q ^ (tok&7)  (pre-swizzled source).
    const uint4* wg = (const uint4*)wfrag;
    const int xtok = wave * 4 + (lane >> 4);                     // local token 0..31
    const float* xsrc = x + (size_t)(T0 + xtok) * DIM + (((lane & 15) ^ (xtok & 7)) << 2);

    // ---- compute role: wave = (mhalf, ntile-pair) ----
    const int mhalf = wave & 1, g = wave >> 1;
    const int nt0 = g, nt1 = g + 4;
    const bool has3 = (g == 0);
    const int ctok = mhalf * 16 + l15;     // token this lane computes
    const int csw = ctok & 7;

    f32x4 acc0 = (f32x4){0.f,0.f,0.f,0.f};
    f32x4 acc1 = (f32x4){0.f,0.f,0.f,0.f};
    f32x4 acc2 = (f32x4){0.f,0.f,0.f,0.f};

    auto stage = [&](int it) {
        char* buf = smem + (it % 3) * BUFB;
        const uint4* wslab = wg + (size_t)it * WCELLS;
        GLOAD_LDS(wslab + (wave * 2) * 64 + lane,     buf + (wave * 2) * 1024);
        GLOAD_LDS(wslab + (wave * 2 + 1) * 64 + lane, buf + (wave * 2 + 1) * 1024);
        if (wave < 2)
            GLOAD_LDS(wslab + (16 + wave) * 64 + lane, buf + (16 + wave) * 1024);
        GLOAD_LDS(xsrc + it * BK, buf + 18432 + wave * 1024);
    };

    // prologue: fill pipeline 2 deep
    stage(0);
    stage(1);

    #pragma unroll
    for (int it = 0; it < NITER; ++it) {
        // drain exactly buffer `it`'s loads (keep it+1's in flight); last iter: full drain
        if (it == NITER - 1)      asm volatile("s_waitcnt vmcnt(0)" ::: "memory");
        else if (wave < 2)        asm volatile("s_waitcnt vmcnt(4)" ::: "memory");
        else                      asm volatile("s_waitcnt vmcnt(3)" ::: "memory");
        __builtin_amdgcn_s_barrier();
        __builtin_amdgcn_sched_barrier(0);

        const char* buf = smem + (it % 3) * BUFB;
        const uint4* wb = (const uint4*)buf;
        const char* xb = buf + 18432;
        #pragma unroll
        for (int ks = 0; ks < 2; ++ks) {
            const int q0 = ks * 8 + lq * 2;
            uint4 xlo = *(const uint4*)(xb + ctok * 256 + ((q0 ^ csw) << 4));
            uint4 xhi = *(const uint4*)(xb + ctok * 256 + (((q0 + 1) ^ csw) << 4));
            union { unsigned u[4]; bf16x8 v; } af;
            af.u[0] = (xlo.x >> 16) | (xlo.y & 0xFFFF0000u);
            af.u[1] = (xlo.z >> 16) | (xlo.w & 0xFFFF0000u);
            af.u[2] = (xhi.x >> 16) | (xhi.y & 0xFFFF0000u);
            af.u[3] = (xhi.z >> 16) | (xhi.w & 0xFFFF0000u);
            bf16x8 b0 = *(const bf16x8*)&wb[(ks * 9 + nt0) * 64 + lane];
            bf16x8 b1v = *(const bf16x8*)&wb[(ks * 9 + nt1) * 64 + lane];
            acc0 = __builtin_amdgcn_mfma_f32_16x16x32_bf16(af.v, b0, acc0, 0, 0, 0);
            acc1 = __builtin_amdgcn_mfma_f32_16x16x32_bf16(af.v, b1v, acc1, 0, 0, 0);
            if (has3) {
                bf16x8 b2v = *(const bf16x8*)&wb[(ks * 9 + 8) * 64 + lane];
                acc2 = __builtin_amdgcn_mfma_f32_16x16x32_bf16(af.v, b2v, acc2, 0, 0, 0);
            }
        }
        if (it + 2 < NITER) stage(it + 2);
    }

    // dump accumulators into slog (union with buf0; compute(31) read buf1 only -> safe)
    float* slog = (float*)smem;            // [32][145]
    float* rp_s = (float*)(smem + BUFB);   // [32][17]
    #pragma unroll
    for (int r = 0; r < 4; ++r) {
        const int row = mhalf * 16 + lq * 4 + r;
        slog[row * 145 + nt0 * 16 + l15] = acc0[r];
        slog[row * 145 + nt1 * 16 + l15] = acc1[r];
        if (has3) slog[row * 145 + 8 * 16 + l15] = acc2[r];
    }
    __syncthreads();

    // parallel epilogue: 32 groups of 16 lanes; group t handles token t
    {
        const int t = tid >> 4;
        const int q = tid & 15;
        const int tok = T0 + t;
        const float* o = slog + t * 145;

        float4 b1v = ((const float4*)b1)[q];
        float4 w2v = ((const float4*)W2)[q];
        float part;
        {
            float h0 = o[q * 4 + 0] + b1v.x; h0 = h0 > 0.f ? h0 : 0.f;
            float h1 = o[q * 4 + 1] + b1v.y; h1 = h1 > 0.f ? h1 : 0.f;
            float h2 = o[q * 4 + 2] + b1v.z; h2 = h2 > 0.f ? h2 : 0.f;
            float h3 = o[q * 4 + 3] + b1v.w; h3 = h3 > 0.f ? h3 : 0.f;
            part = h0 * w2v.x + h1 * w2v.y + h2 * w2v.z + h3 * w2v.w;
        }
        #pragma unroll
        for (int off = 8; off; off >>= 1) part += __shfl_xor(part, off, 16);
        float z = b2[0] + part;
        float c = 1.f / (1.f + expf(-z));
        int mx = maxE[0], mn = minE[0];
        float y = c * (float)mx;
        int k = (int)y; k = k < mn ? mn : (k > mx ? mx : k);
        int kl = (int)(y - KEPS); kl = kl < mn ? mn : (kl > mx ? mx : kl);
        int kh = (int)(y + KEPS); kh = kh < mn ? mn : (kh > mx ? mx : kh);
        bool flagK = (kl != kh);
        float u2 = (k >= 2) ? 1.f : 0.f;

        float gl0 = o[HH + 0], gl1 = o[HH + 1], gl2 = o[HH + 2], gl3 = o[HH + 3];
        float gm = gl0; int gi = 0;
        if (gl1 > gm) { gm = gl1; gi = 1; }
        if (gl2 > gm) { gm = gl2; gi = 2; }
        if (gl3 > gm) { gm = gl3; gi = 3; }
        float g2 = -INFINITY;
        if (gi != 0 && gl0 > g2) g2 = gl0;
        if (gi != 1 && gl1 > g2) g2 = gl1;
        if (gi != 2 && gl2 > g2) g2 = gl2;
        if (gi != 3 && gl3 > g2) g2 = gl3;
        bool flagG = (gm - g2) < TAU;
        float gsum = expf(gl0 - gm) + expf(gl1 - gm) + expf(gl2 - gm) + expf(gl3 - gm);
        float gp = 1.f / gsum;

        float el = o[HH + NG + gi * EPG + q];
        float v1v = el; int i1 = q;
        #pragma unroll
        for (int off = 8; off; off >>= 1) {
            float ov = __shfl_xor(v1v, off, 16);
            int   oi = __shfl_xor(i1, off, 16);
            if (ov > v1v || (ov == v1v && oi < i1)) { v1v = ov; i1 = oi; }
        }
        float v2v = (q == i1) ? -INFINITY : el; int i2 = q;
        #pragma unroll
        for (int off = 8; off; off >>= 1) {
            float ov = __shfl_xor(v2v, off, 16);
            int   oi = __shfl_xor(i2, off, 16);
            if (ov > v2v || (ov == v2v && oi < i2)) { v2v = ov; i2 = oi; }
        }
        float e3v = (q == i1 || q == i2) ? -INFINITY : el;
        #pragma unroll
        for (int off = 8; off; off >>= 1)
            e3v = fmaxf(e3v, __shfl_xor(e3v, off, 16));
        bool flagE = ((v1v - v2v) < TAU) || (u2 > 0.f && (v2v - e3v) < TAU);

        float ep = expf(el - v1v);
        float es = ep;
        #pragma unroll
        for (int off = 8; off; off >>= 1) es += __shfl_xor(es, off, 16);
        float inv = 1.f / es;
        rp_s[t * 17 + q] = gp * ep * inv;

        if (q == 0) {
            float v1p = inv;
            float v2p = expf(v2v - v1v) * inv;
            float denom = v1p + v2p * u2;
            sc_n1[t] = v1p / denom; sc_n2[t] = v2p * u2 / denom; sc_u2[t] = u2;
            sc_e1[t] = gi * EPG + i1; sc_e2[t] = gi * EPG + i2;
            if (flagK || flagG || flagE) {
                int p = atomicAdd(cnt, 1);
                int fl = (flagG ? 1 : 0) | (flagE ? 2 : 0) | (flagK ? 4 : 0);
                list[p] = make_int4(tok, fl, (int)u2, 0);
            }
        }
    }
    __syncthreads();

    float* outD = out;
    float* outC = out + (size_t)T_TOKENS * NE;
    float* outR = out + (size_t)2 * T_TOKENS * NE;
    for (int idx = tid; idx < BM * NE; idx += 512) {
        int t = idx >> 6, e = idx & 63;
        int e1i = sc_e1[t], e2i = sc_e2[t];
        int gi = e1i >> 4;
        float disp = (e == e1i ? 1.f : 0.f) + (e == e2i ? sc_u2[t] : 0.f);
        float comb = (e == e1i ? sc_n1[t] : 0.f) + (e == e2i ? sc_n2[t] : 0.f);
        float rpv  = ((e >> 4) == gi) ? ((float*)(smem + BUFB))[t * 17 + (e & 15)] : 0.f;
        size_t ob = (size_t)(T0 + t) * NE + e;
        outD[ob] = disp; outC[ob] = comb; outR[ob] = rpv;
        atomicAdd(&s_usage[e], disp);
        atomicAdd(&s_rp[e], rpv);
    }
    __syncthreads();
    if (tid < NE) {
        atomicAdd(&sums[tid], s_usage[tid]);
        atomicAdd(&sums[NE + tid], s_rp[tid]);
    }
}

// parallel fixup: one block (4 waves) per flagged token
__global__ __launch_bounds__(256, 4) void moe_fix(
    const float* __restrict__ x, const float* __restrict__ Wg,
    const float* __restrict__ We, const float* __restrict__ W1,
    const float* __restrict__ b1, const float* __restrict__ W2,
    const float* __restrict__ b2, const int* __restrict__ minE,
    const int* __restrict__ maxE, float* __restrict__ out,
    float* __restrict__ sums, const int* __restrict__ cnt,
    const int4* __restrict__ list) {
    __shared__ float gl_s[NG];
    __shared__ float h_s[HH];
    __shared__ float el_s[EPG];
    __shared__ float rp_row[EPG];
    __shared__ int   s_gi;
    __shared__ float s_u2, s_gp;
    __shared__ int   s_e1, s_e2;
    __shared__ float s_n1, s_n2;

    const int tid = threadIdx.x;
    const int wave = tid >> 6, lane = tid & 63;
    const int n = *cnt;

    for (int i = blockIdx.x; i < n; i += gridDim.x) {
        const int4 ent = list[i];
        const int tok = ent.x, fl = ent.y;
        const float u2_in = (float)ent.z;

        const float* xrow = x + (size_t)tok * DIM;
        float xr[32];
        #pragma unroll
        for (int m = 0; m < 32; ++m) xr[m] = xrow[lane + m * 64];

        auto dotf = [&](const float* w) -> float {
            float s = 0.f;
            #pragma unroll
            for (int m = 0; m < 32; ++m) s = fmaf(xr[m], w[lane + m * 64], s);
            #pragma unroll
            for (int off = 32; off; off >>= 1) s += __shfl_xor(s, off, 64);
            return s;
        };

        {
            float g = dotf(Wg + (size_t)wave * DIM);
            if (lane == 0) gl_s[wave] = g;
        }
        if (fl & 4) {
            for (int j = wave; j < HH; j += 4) {
                float hv = dotf(W1 + (size_t)j * DIM);
                if (lane == 0) h_s[j] = hv;
            }
        }
        __syncthreads();

        if (tid == 0) {
            float gm = -INFINITY; int gi = 0;
            #pragma unroll
            for (int g = 0; g < NG; ++g)
                if (gl_s[g] > gm) { gm = gl_s[g]; gi = g; }
            float gsum = 0.f;
            #pragma unroll
            for (int g = 0; g < NG; ++g) gsum += expf(gl_s[g] - gm);
            s_gp = 1.f / gsum;
            s_gi = gi;
            float u2 = u2_in;
            if (fl & 4) {
                float z = b2[0];
                for (int j = 0; j < HH; ++j) {
                    float h = h_s[j] + b1[j];
                    z = fmaf(W2[j], h > 0.f ? h : 0.f, z);
                }
                float c = 1.f / (1.f + expf(-z));
                int mx = maxE[0], mn = minE[0];
                int k = (int)(c * (float)mx);
                k = k < mn ? mn : (k > mx ? mx : k);
                u2 = (k >= 2) ? 1.f : 0.f;
            }
            s_u2 = u2;
        }
        __syncthreads();

        const int gi = s_gi;
        for (int j = wave; j < EPG; j += 4) {
            float e = dotf(We + (size_t)(gi * EPG + j) * DIM);
            if (lane == 0) el_s[j] = e;
        }
        __syncthreads();

        if (tid == 0) {
            float e1 = -INFINITY, e2v = -INFINITY; int i1 = 0, i2 = 0;
            #pragma unroll
            for (int j = 0; j < EPG; ++j) {
                float v = el_s[j];
                if (v > e1)       { e2v = e1; i2 = i1; e1 = v; i1 = j; }
                else if (v > e2v) { e2v = v; i2 = j; }
            }
            float es = 0.f;
            #pragma unroll
            for (int j = 0; j < EPG; ++j) {
                float e = expf(el_s[j] - e1);
                rp_row[j] = e;
                es += e;
            }
            float inv = 1.f / es;
            float gp = s_gp;
            #pragma unroll
            for (int j = 0; j < EPG; ++j) rp_row[j] *= inv * gp;
            float v1 = expf(el_s[i1] - e1) * inv;
            float v2 = expf(el_s[i2] - e1) * inv;
            float u2 = s_u2;
            float denom = v1 + v2 * u2;
            s_n1 = v1 / denom; s_n2 = v2 * u2 / denom;
            s_e1 = gi * EPG + i1; s_e2 = gi * EPG + i2;
        }
        __syncthreads();

        if (tid < NE) {
            const int e = tid;
            float u2 = s_u2;
            float newD = (e == s_e1 ? 1.f : 0.f) + (e == s_e2 ? u2 : 0.f);
            float newC = (e == s_e1 ? s_n1 : 0.f) + (e == s_e2 ? s_n2 : 0.f);
            float newR = ((e >> 4) == gi) ? rp_row[e & 15] : 0.f;
            size_t ob = (size_t)tok * NE + e;
            float oldD = out[ob];
            float oldR = out[(size_t)2 * T_TOKENS * NE + ob];
            out[ob] = newD;
            out[(size_t)T_TOKENS * NE + ob] = newC;
            out[(size_t)2 * T_TOKENS * NE + ob] = newR;
            float dD = newD - oldD, dR = newR - oldR;
            if (dD != 0.f) atomicAdd(&sums[e], dD);
            if (dR != 0.f) atomicAdd(&sums[NE + e], dR);
        }
        __syncthreads();
    }
}

__global__ void moe_finalize(const float* __restrict__ sums, float* __restrict__ out) {
    int l = threadIdx.x;
    float v = sums[l] * sums[NE + l];
    #pragma unroll
    for (int off = 32; off; off >>= 1) v += __shfl_down(v, off, 64);
    if (l == 0) {
        float N = (float)T_TOKENS;
        out[(size_t)3 * T_TOKENS * NE] = v * (float)NE / (N * N);
    }
}

extern "C" void kernel_launch(void* const* d_in, const int* in_sizes, int n_in,
                              void* d_out, int out_size, void* d_ws, size_t ws_size,
                              hipStream_t stream) {
    const float* x  = (const float*)d_in[0];
    const float* Wg = (const float*)d_in[1];
    const float* We = (const float*)d_in[2];
    const float* W1 = (const float*)d_in[3];
    const float* b1 = (const float*)d_in[4];
    const float* W2 = (const float*)d_in[5];
    const float* b2 = (const float*)d_in[6];
    const int* minE = (const int*)d_in[7];
    const int* maxE = (const int*)d_in[8];
    float* out = (float*)d_out;
    float* ws  = (float*)d_ws;

    float* wfrag = ws;
    float* sums  = ws + SUM_OFF;
    int*   cnt   = (int*)(ws + CNT_OFF);
    int4*  list  = (int4*)(ws + LIST_OFF);

    moe_prep<<<64 * NT, 64, 0, stream>>>(Wg, We, W1, wfrag, sums, cnt);
    moe_fused<<<T_TOKENS / BM, 512, 0, stream>>>(x, wfrag, b1, W2, b2, minE, maxE,
                                                 out, sums, cnt, list);
    moe_fix<<<2048, 256, 0, stream>>>(x, Wg, We, W1, b1, W2, b2, minE, maxE,
                                      out, sums, cnt, list);
    moe_finalize<<<1, 64, 0, stream>>>(sums, out);
}